// Round 3
// baseline (285.129 us; speedup 1.0000x reference)
//
#include <hip/hip_runtime.h>
#include <math.h>

#define B_      16
#define K_      200000
#define N_      40
#define TPB     256
#define ITEMS   4
#define TILE    (TPB * ITEMS)                 // 1024 elements per block
#define NBX     ((K_ + TILE - 1) / TILE)      // 196
#define NBLOCKS (NBX * B_)                    // 3136
#define NE      (2 * N_)                      // 80 endpoints
#define NACC    7                             // live accumulators
#define PACC    8                             // padded storage stride (8B-pair loads)

// ws layout:
//   [0, PART_BYTES)            : per-block partials (NBLOCKS x PACC floats, q=7 pad)
//   [TBL_OFF + b*TBL_STRIDE..) : per-batch tables:
//       float  bp[80]   @ +0     sorted endpoints
//       float4 at4[80]  @ +320   (tl,tr,lab,valid) winner when c == bp[i]
//       float4 gap4[81] @ +1600  (tl,tr,lab,valid) winner for open gap (bp[i-1],bp[i])
//   [CNT_OFF]                  : int done-counter (zeroed by msl_setup)
#define PART_BYTES  (NBLOCKS * PACC * 4)      // 100,352
#define TBL_OFF     PART_BYTES
#define TBL_STRIDE  3072
#define CNT_OFF     (TBL_OFF + B_ * TBL_STRIDE)   // 149,504; total ws use 149,508 B

typedef float v2f __attribute__((ext_vector_type(2)));

__device__ __forceinline__ v2f ld2(const float* p) {
    v2f r;
    asm volatile("global_load_dwordx2 %0, %1, off" : "=v"(r) : "v"(p) : "memory");
    return r;
}
__device__ __forceinline__ float ld1(const float* p) {
    float r;
    asm volatile("global_load_dword %0, %1, off" : "=v"(r) : "v"(p) : "memory");
    return r;
}
// counted wait + scheduling fence (rule #18: sched_barrier required after waitcnt)
#define WAITV(N) do { asm volatile("s_waitcnt vmcnt(" #N ")" ::: "memory"); \
                      __builtin_amdgcn_sched_barrier(0); } while (0)

__global__ __launch_bounds__(256) void msl_setup(
    const float* __restrict__ targets, char* __restrict__ ws)
{
    __shared__ float tl0[N_], tr0[N_], lb0[N_], ar0[N_];
    __shared__ float stl[N_], str[N_], slb[N_];
    __shared__ float ep[NE], bp[NE];
    const int b = blockIdx.x, t = threadIdx.x;

    if (b == 0 && t == 0) *(int*)(ws + CNT_OFF) = 0;   // done-counter init

    if (t < N_) {
        const float* tg = targets + (b * N_ + t) * 3;
        const float tl = tg[0], tr = tg[1];
        tl0[t] = tl; tr0[t] = tr; lb0[t] = tg[2];
        ar0[t] = (tr - tl) * 256.0f;
    }
    __syncthreads();

    // stable rank-sort segments by area (tie: original index) -> priority order
    if (t < N_) {
        const float an = ar0[t];
        int r = 0;
        #pragma unroll
        for (int m = 0; m < N_; ++m) {
            const float am = ar0[m];
            r += (am < an) || (am == an && m < t);
        }
        stl[r] = tl0[t]; str[r] = tr0[t]; slb[r] = lb0[t];
    }
    if (t < NE) ep[t] = (t < N_) ? tl0[t] : tr0[t - N_];
    __syncthreads();

    // rank-sort endpoints
    if (t < NE) {
        const float v = ep[t];
        int r = 0;
        #pragma unroll
        for (int m = 0; m < NE; ++m) {
            const float vm = ep[m];
            r += (vm < v) || (vm == v && m < t);
        }
        bp[r] = v;
    }
    __syncthreads();

    char* tb = ws + TBL_OFF + b * TBL_STRIDE;

    // point winners: first (priority-order) segment with stl<=v<=str
    if (t < NE) {
        const float v = bp[t];
        int w = N_;
        for (int s = N_ - 1; s >= 0; --s)
            w = (stl[s] <= v && v <= str[s]) ? s : w;
        const bool ok = (w < N_);
        const int si = ok ? w : 0;
        ((float4*)(tb + 320))[t] = ok
            ? make_float4(stl[si], str[si], slb[si], 1.0f)
            : make_float4(0.f, 0.f, 0.f, 0.f);
        ((float*)tb)[t] = v;
    }
    // gap winners: open interval (a, bb) entirely inside [stl, str]
    if (t >= 128 && t < 128 + NE + 1) {
        const int g = t - 128;                 // 0..80
        const float a  = g ? bp[g - 1] : -INFINITY;
        const float bb = (g < NE) ? bp[g] : INFINITY;
        int w = N_;
        for (int s = N_ - 1; s >= 0; --s)
            w = (stl[s] <= a && bb <= str[s]) ? s : w;
        const bool ok = (w < N_);
        const int si = ok ? w : 0;
        ((float4*)(tb + 1600))[g] = ok
            ? make_float4(stl[si], str[si], slb[si], 1.0f)
            : make_float4(0.f, 0.f, 0.f, 0.f);
    }
}

__device__ __forceinline__ void elem_accum(
    const float c, const float pl, const float pr,
    const float x0, const float x1,
    const float p0, const float p1,
    const float y0, const float y1,
    const float lg,
    const int base, const int end,
    const float* __restrict__ s_bp,
    const float4* __restrict__ s_tab,          // [0..79]=at, [80..160]=gap
    float& f0, float& f1, float& f2, float& f3,
    float& f4, float& f5, float& f6)
{
    const float EPS = 1.1920928955078125e-7f;  // FLT_EPSILON

    // ---- match: pos = #bp <= c; in-range bp are contiguous [base,end) ----
    int pos = base; bool eq = false;
    for (int i = base; i < end; ++i) {           // block-uniform bounds
        const float v = s_bp[i];                 // broadcast read
        pos += (v <= c) ? 1 : 0;
        eq  |= (v == c);
    }
    // single ds_read_b128 from merged table
    const int idx = eq ? (pos - 1) : (NE + pos);
    const float4 sg = s_tab[idx];

    const float tl = sg.x, tr = sg.y;
    const int conf_t = (int)sg.z;                // 0 when unmatched
    const float lt0 = (c - tl) * 256.0f;
    const float lt1 = (tr - c) * 256.0f;

    // ---- iou(loc, loc_t) ----
    const float inter = fminf(pl, lt0) + fminf(pr, lt1);
    const float uni   = pl + pr + (lt0 + lt1) - inter;
    const float iou   = __fdividef(inter, fmaxf(uni, EPS));
    const int pconf_t = (iou < 0.5f) ? 0 : conf_t;

    const float posf = (conf_t > 0) ? 1.0f : 0.0f;
    const float ppf  = (pconf_t > 0) ? 1.0f : 0.0f;

    // GIoU (pos only)
    const float ac   = fmaxf(pl, lt0) + fmaxf(pr, lt1);
    const float giou = iou - __fdividef(ac - uni, fmaxf(ac, EPS));
    f0 += (1.0f - giou) * posf;

    // prop loc L1 (prop-pos only)
    const float prop_w = pl + pr;
    const float rw = __fdividef(1.0f, 0.5f * prop_w);
    const float plt0 = (lt0 - pl) * rw;
    const float plt1 = (lt1 - pr) * rw;
    f2 += (fabsf(p0 - plt0) + fabsf(p1 - plt1)) * ppf;

    // centerness BCE (pos only)
    const float cur0 = 0.5f * prop_w * p0 + pl;
    const float cur1 = 0.5f * prop_w * p1 + pr;
    const float inter2 = fminf(cur0, lt0) + fminf(cur1, lt1);
    const float uni2   = cur0 + cur1 + (lt0 + lt1) - inter2;
    const float iou2   = fmaxf(__fdividef(inter2, fmaxf(uni2, EPS)), 0.0f);
    const float bce = fmaxf(lg, 0.0f) - lg * iou2
                      + __logf(1.0f + __expf(-fabsf(lg)));
    f4 += bce * posf;

    // focal on conf (all elements)
    {
        const float xt = conf_t ? x1 : x0;
        const float xo = conf_t ? x0 : x1;
        const float pt = __fdividef(1.0f, 1.0f + __expf(xo - xt)) + 1e-6f;
        const float al = conf_t ? 0.75f : 0.25f;
        const float om = 1.0f - pt;
        f1 += -om * om * al * __logf(pt);
    }
    // focal on prop_conf (all elements)
    {
        const float xt = pconf_t ? y1 : y0;
        const float xo = pconf_t ? y0 : y1;
        const float pt = __fdividef(1.0f, 1.0f + __expf(xo - xt)) + 1e-6f;
        const float al = pconf_t ? 0.75f : 0.25f;
        const float om = 1.0f - pt;
        f3 += -om * om * al * __logf(pt);
    }

    f5 += posf;
    f6 += ppf;
}

__global__ __launch_bounds__(TPB) void msl_main(
    const float* __restrict__ loc,     // (B,K,2)
    const float* __restrict__ conf,    // (B,K,2)
    const float* __restrict__ ploc,    // (B,K,2)
    const float* __restrict__ pconf,   // (B,K,2)
    const float* __restrict__ center,  // (B,K,1)
    const float* __restrict__ priors,  // (K,1)
    char* __restrict__ ws,
    float* __restrict__ out)
{
    __shared__ float  s_bp[NE];
    __shared__ float4 s_tab[2 * NE + 1];   // [0..79]=at, [80..160]=gap
    __shared__ int    s_cnt[4];            // {base_w0, base_w1, end_w0, end_w1}
    __shared__ float  s_redf[TPB / 64][NACC];
    __shared__ int    s_last;

    const int b = blockIdx.y;
    const int t = threadIdx.x;
    const int kb = blockIdx.x * TILE;
    const int kend = (kb + TILE < K_) ? kb + TILE : K_;

    // ---- single-phase prologue: table loads + ballot counts, ONE barrier ----
    {
        const char* tb = ws + TBL_OFF + b * TBL_STRIDE;
        // waves 0-1 (t<128): load bp (pad >=80 with +INF), ballot vs block range
        if (t < 128) {
            const float v = (t < NE) ? ((const float*)tb)[t] : INFINITY;
            if (t < NE) s_bp[t] = v;
            const float cmin = priors[kb];          // uniform -> s_load
            const float cmax = priors[kend - 1];
            const unsigned long long mlo = __ballot(v < cmin);
            const unsigned long long mhi = __ballot(v <= cmax);
            const int wv = t >> 6;                   // 0 or 1
            if ((t & 63) == 0) {
                s_cnt[wv]     = __popcll(mlo);
                s_cnt[2 + wv] = __popcll(mhi);
            }
        } else if (t < 208) {                        // 80 at4 loads -> s_tab[0..79]
            s_tab[t - 128] = ((const float4*)(tb + 320))[t - 128];
        } else {                                     // 48 threads: gap4[0..47]
            s_tab[NE + (t - 208)] = ((const float4*)(tb + 1600))[t - 208];
        }
        if (t < 33)                                  // gap4[48..80]
            s_tab[NE + 48 + t] = ((const float4*)(tb + 1600))[48 + t];
    }
    __syncthreads();

    const int base = s_cnt[0] + s_cnt[1];            // #bp <  cmin
    const int end  = s_cnt[2] + s_cnt[3];            // #bp <= cmax

    const int bK  = b * K_;
    const int bK2 = bK * 2;

    float f0 = 0.f, f1 = 0.f, f2 = 0.f, f3 = 0.f, f4 = 0.f, f5 = 0.f, f6 = 0.f;

    const int kbase = kb + t;
    if (kb + TILE <= K_) {
        // ---- fast path: FORCED batch of all 24 loads (asm, program-order) ----
        // then counted vmcnt waits: compute item j while items j+1.. in flight
        v2f  l2[ITEMS], cf2[ITEMS], pl2[ITEMS], pc2[ITEMS];
        float lg[ITEMS], cc[ITEMS];
        #pragma unroll
        for (int j = 0; j < ITEMS; ++j) {
            const int k  = kbase + j * TPB;
            const int i2 = bK2 + k * 2;
            l2[j]  = ld2(loc   + i2);
            cf2[j] = ld2(conf  + i2);
            pl2[j] = ld2(ploc  + i2);
            pc2[j] = ld2(pconf + i2);
            lg[j]  = ld1(center + bK + k);
            cc[j]  = ld1(priors + k);
        }
        WAITV(18);   // item0's 6 loads complete; 18 still in flight
        elem_accum(cc[0], l2[0].x, l2[0].y, cf2[0].x, cf2[0].y,
                   pl2[0].x, pl2[0].y, pc2[0].x, pc2[0].y, lg[0],
                   base, end, s_bp, s_tab, f0, f1, f2, f3, f4, f5, f6);
        WAITV(12);
        elem_accum(cc[1], l2[1].x, l2[1].y, cf2[1].x, cf2[1].y,
                   pl2[1].x, pl2[1].y, pc2[1].x, pc2[1].y, lg[1],
                   base, end, s_bp, s_tab, f0, f1, f2, f3, f4, f5, f6);
        WAITV(6);
        elem_accum(cc[2], l2[2].x, l2[2].y, cf2[2].x, cf2[2].y,
                   pl2[2].x, pl2[2].y, pc2[2].x, pc2[2].y, lg[2],
                   base, end, s_bp, s_tab, f0, f1, f2, f3, f4, f5, f6);
        WAITV(0);
        elem_accum(cc[3], l2[3].x, l2[3].y, cf2[3].x, cf2[3].y,
                   pl2[3].x, pl2[3].y, pc2[3].x, pc2[3].y, lg[3],
                   base, end, s_bp, s_tab, f0, f1, f2, f3, f4, f5, f6);
    } else {
        // ---- tail blocks (16/3136): plain bounds-checked loop ----
        #pragma unroll
        for (int j = 0; j < ITEMS; ++j) {
            const int k = kbase + j * TPB;
            if (k >= K_) continue;
            const int i2 = bK2 + k * 2;
            const float2 a  = *(const float2*)(loc   + i2);
            const float2 cf = *(const float2*)(conf  + i2);
            const float2 pp = *(const float2*)(ploc  + i2);
            const float2 pc = *(const float2*)(pconf + i2);
            elem_accum(priors[k], a.x, a.y, cf.x, cf.y,
                       pp.x, pp.y, pc.x, pc.y, center[bK + k],
                       base, end, s_bp, s_tab, f0, f1, f2, f3, f4, f5, f6);
        }
    }

    // ---- block reduction (f32 wave tree, f64 cross-wave) -> partials ----
    {
        float vals[NACC] = {f0, f1, f2, f3, f4, f5, f6};
        const int wave = t >> 6, lane = t & 63;
        #pragma unroll
        for (int q = 0; q < NACC; ++q) {
            float v = vals[q];
            #pragma unroll
            for (int off = 32; off > 0; off >>= 1)
                v += __shfl_down(v, off, 64);
            if (lane == 0) s_redf[wave][q] = v;
        }
    }
    __syncthreads();
    if (t == 0) {
        float* partials = (float*)ws;
        const int bid = blockIdx.y * gridDim.x + blockIdx.x;
        #pragma unroll
        for (int q = 0; q < NACC; ++q) {
            double s = 0.0;
            #pragma unroll
            for (int w2 = 0; w2 < TPB / 64; ++w2) s += (double)s_redf[w2][q];
            partials[bid * PACC + q] = (float)s;
        }
        __threadfence();                               // release partials
        const int old = atomicAdd((int*)(ws + CNT_OFF), 1);   // device scope
        s_last = (old == NBLOCKS - 1) ? 1 : 0;
    }
    __syncthreads();

    // ---- last block: final reduction (deterministic, same order as before) ----
    if (s_last) {
        __threadfence();                               // acquire
        const float* partials = (const float*)ws;
        double acc[NACC] = {0, 0, 0, 0, 0, 0, 0};
        for (int i = t; i < NBLOCKS; i += TPB) {
            const float* row = partials + (i << 3);    // PACC==8, 32B-aligned
            // AGENT-scope loads bypass non-coherent per-XCD L2 (coherence
            // point = memory-side Infinity Cache)
            const unsigned long long u01 = __hip_atomic_load(
                (const unsigned long long*)(row + 0), __ATOMIC_RELAXED, __HIP_MEMORY_SCOPE_AGENT);
            const unsigned long long u23 = __hip_atomic_load(
                (const unsigned long long*)(row + 2), __ATOMIC_RELAXED, __HIP_MEMORY_SCOPE_AGENT);
            const unsigned long long u45 = __hip_atomic_load(
                (const unsigned long long*)(row + 4), __ATOMIC_RELAXED, __HIP_MEMORY_SCOPE_AGENT);
            const float p6 = __hip_atomic_load(
                row + 6, __ATOMIC_RELAXED, __HIP_MEMORY_SCOPE_AGENT);
            const float2 p01 = __builtin_bit_cast(float2, u01);
            const float2 p23 = __builtin_bit_cast(float2, u23);
            const float2 p45 = __builtin_bit_cast(float2, u45);
            acc[0] += (double)p01.x; acc[1] += (double)p01.y;
            acc[2] += (double)p23.x; acc[3] += (double)p23.y;
            acc[4] += (double)p45.x; acc[5] += (double)p45.y;
            acc[6] += (double)p6;
        }
        __shared__ double s_fin[TPB / 64][NACC];
        const int wave = t >> 6, lane = t & 63;
        #pragma unroll
        for (int q = 0; q < NACC; ++q) {
            double v = acc[q];
            #pragma unroll
            for (int off = 32; off > 0; off >>= 1)
                v += __shfl_down(v, off, 64);
            if (lane == 0) s_fin[wave][q] = v;
        }
        __syncthreads();
        if (t == 0) {
            double s[NACC];
            #pragma unroll
            for (int q = 0; q < NACC; ++q) {
                double v = 0.0;
                #pragma unroll
                for (int w = 0; w < TPB / 64; ++w) v += s_fin[w][q];
                s[q] = v;
            }
            const double Np = fmax(s[5], 1.0);
            const double PN = fmax(s[6], 1.0);
            out[0] = (float)(s[0] / Np);
            out[1] = (float)(s[1] / Np);
            out[2] = (float)(s[2] / PN);
            out[3] = (float)(s[3] / PN);
            out[4] = (float)(s[4] / Np);
        }
    }
}

extern "C" void kernel_launch(void* const* d_in, const int* in_sizes, int n_in,
                              void* d_out, int out_size, void* d_ws, size_t ws_size,
                              hipStream_t stream) {
    const float* loc     = (const float*)d_in[0];
    const float* conf    = (const float*)d_in[1];
    const float* ploc    = (const float*)d_in[2];
    const float* pconf   = (const float*)d_in[3];
    const float* center  = (const float*)d_in[4];
    const float* priors  = (const float*)d_in[5];
    const float* targets = (const float*)d_in[6];
    char* ws = (char*)d_ws;   // uses 149,508 bytes

    msl_setup<<<B_, 256, 0, stream>>>(targets, ws);
    dim3 grid(NBX, B_);
    msl_main<<<grid, TPB, 0, stream>>>(loc, conf, ploc, pconf, center, priors,
                                       ws, (float*)d_out);
}